// Round 10
// baseline (217.277 us; speedup 1.0000x reference)
//
#include <hip/hip_runtime.h>
#include <math.h>

typedef long long ll;
typedef unsigned int u32;
typedef unsigned short u16;
typedef __attribute__((ext_vector_type(8))) short short8;
typedef __attribute__((ext_vector_type(4))) float f32x4;

#define NBLK 512          // partition blocks (2 blocks/CU for ehist/escatter)
#define MAXBUK 512        // supports N <= 131072
#define CHUNK_MAX 4096    // LDS edge buffer; supports EP <= NBLK*CHUNK_MAX

__device__ __forceinline__ int load_idx(const void* p, int i, int is64) {
  return is64 ? (int)((const ll*)p)[i] : ((const int*)p)[i];
}

__device__ __forceinline__ u16 f2bf(float f) {
  u32 u = __float_as_uint(f);
  u += 0x7FFFu + ((u >> 16) & 1u);
  return (u16)(u >> 16);
}

// ---------- prep: W1->bf16^T + detect(parallel) + zero pool/gbin ----------
__global__ __launch_bounds__(256) void prep_kernel(
    const void* __restrict__ eidx, int ne2, const void* __restrict__ batch, int nb,
    const float* __restrict__ W1, u16* __restrict__ Wtb,
    float* __restrict__ pool, int* __restrict__ gbin, int* __restrict__ flags) {
  int blk = blockIdx.x, t = threadIdx.x;
  if (blk < 64) {
    int g = blk * 256 + t;          // 16384 elements of W1[k][j]
    int k = g >> 7, j = g & 127;
    Wtb[j * 128 + k] = f2bf(W1[g]);
  } else {
    if (t < 192) pool[t] = 0.f;
    if (t < 64) gbin[t] = 0;
    ll v = 0;
    if (t < 16) {
      int i = (int)((ll)(t + 1) * (ne2 / 2 - 1) / 16);
      v = ((const ll*)eidx)[i];
    } else if (t < 32) {
      int i = (int)((ll)(t - 15) * (nb / 2 - 1) / 16);
      v = ((const ll*)batch)[i];
    }
    bool bad = (v < 0 || v >= (1LL << 31));
    unsigned long long mask = __ballot(bad);
    if (t == 0) {
      flags[0] = (mask & 0xFFFFull) ? 0 : 1;          // edge_index is64
      flags[1] = (mask & 0xFFFF0000ull) ? 0 : 1;      // batch is64
    }
  }
}

// ---------- K1: h = x @ W1 via MFMA bf16 (f32 acc; fused a_src1/a_dst1) ----------
__global__ __launch_bounds__(256) void gemm1_kernel(
    const float* __restrict__ x, const u16* __restrict__ Wtb,
    const float* __restrict__ att_src, const float* __restrict__ att_dst,
    u16* __restrict__ h, float* __restrict__ a_src, float* __restrict__ a_dst,
    int nn) {
  __shared__ __align__(16) char smem[64 * 136 * 2 + 128 * 136 * 2];  // 52224 B
  u16* xs = (u16*)smem;                       // [64][136]
  u16* Wt = (u16*)(smem + 64 * 136 * 2);      // [128][136]  Wt[j][k]
  float* hs = (float*)smem;                   // [64][132]   (overlay)
  int t = threadIdx.x;
  int n0 = blockIdx.x * 64;

  const uint4* W4 = (const uint4*)Wtb;        // 2048 uint4
  #pragma unroll
  for (int p = 0; p < 8; ++p) {
    int i = t + p * 256;
    int j = i >> 4, kc = (i & 15) * 8;
    *(uint4*)&Wt[j * 136 + kc] = W4[i];
  }
  #pragma unroll
  for (int p = 0; p < 4; ++p) {
    int row = p * 16 + (t >> 4);
    int c = t & 15;
    int gn = n0 + row;
    uint4 pk = make_uint4(0u, 0u, 0u, 0u);
    if (gn < nn) {
      const float4* xp = (const float4*)(x + (size_t)gn * 128 + c * 8);
      float4 f0 = xp[0], f1 = xp[1];
      pk.x = (u32)f2bf(f0.x) | ((u32)f2bf(f0.y) << 16);
      pk.y = (u32)f2bf(f0.z) | ((u32)f2bf(f0.w) << 16);
      pk.z = (u32)f2bf(f1.x) | ((u32)f2bf(f1.y) << 16);
      pk.w = (u32)f2bf(f1.z) | ((u32)f2bf(f1.w) << 16);
    }
    *(uint4*)&xs[row * 136 + c * 8] = pk;
  }
  __syncthreads();

  int lane = t & 63, wid = t >> 6;
  int lrow = lane & 15, lq = lane >> 4;
  short8 a[4];
  #pragma unroll
  for (int ks = 0; ks < 4; ++ks) {
    int row = wid * 16 + lrow;
    a[ks] = *(const short8*)&xs[row * 136 + ks * 32 + lq * 8];
  }
  f32x4 c[8];
  #pragma unroll
  for (int jt = 0; jt < 8; ++jt) c[jt] = (f32x4)(0.f);
  #pragma unroll
  for (int jt = 0; jt < 8; ++jt) {
    int j = jt * 16 + lrow;
    #pragma unroll
    for (int ks = 0; ks < 4; ++ks) {
      short8 b = *(const short8*)&Wt[j * 136 + ks * 32 + lq * 8];
      c[jt] = __builtin_amdgcn_mfma_f32_16x16x32_bf16(a[ks], b, c[jt], 0, 0, 0);
    }
  }
  __syncthreads();

  #pragma unroll
  for (int jt = 0; jt < 8; ++jt) {
    #pragma unroll
    for (int r = 0; r < 4; ++r) {
      hs[(wid * 16 + lq * 4 + r) * 132 + jt * 16 + lrow] = c[jt][r];
    }
  }
  __syncthreads();

  int q = t & 31, p = t >> 5;
  const float4 as4 = ((const float4*)att_src)[q];
  const float4 ad4 = ((const float4*)att_dst)[q];
  int head = q >> 2;
  #pragma unroll
  for (int rr = 0; rr < 8; ++rr) {
    int row = rr * 8 + p;
    int n = n0 + row;
    float4 v = *(const float4*)&hs[row * 132 + q * 4];
    float s = v.x * as4.x + v.y * as4.y + v.z * as4.z + v.w * as4.w;
    float d = v.x * ad4.x + v.y * ad4.y + v.z * ad4.z + v.w * ad4.w;
    s += __shfl_xor(s, 1); s += __shfl_xor(s, 2);
    d += __shfl_xor(d, 1); d += __shfl_xor(d, 2);
    if (n < nn) {
      uint2 pk;
      pk.x = (u32)f2bf(v.x) | ((u32)f2bf(v.y) << 16);
      pk.y = (u32)f2bf(v.z) | ((u32)f2bf(v.w) << 16);
      ((uint2*)(h + (size_t)n * 128))[q] = pk;
      if ((q & 3) == 0) { a_src[n * 8 + head] = s; a_dst[n * 8 + head] = d; }
    }
  }
}

// ---------- per-block LDS histogram of dst buckets ----------
__global__ __launch_bounds__(512) void ehist_kernel(
    const void* __restrict__ eidx, int E, int EP, int chunk,
    const int* __restrict__ flags, int* __restrict__ hist_g, int nbuk) {
  __shared__ int cnt[MAXBUK];
  int t = threadIdx.x, blk = blockIdx.x;
  if (t < MAXBUK) cnt[t] = 0;
  __syncthreads();
  int lo = blk * chunk, hi = min(lo + chunk, EP);
  int is64 = flags[0];
  for (int i = lo + t; i < hi; i += 512) {
    int d = (i < E) ? load_idx(eidx, E + i, is64) : (i - E);
    atomicAdd(&cnt[d >> 8], 1);
  }
  __syncthreads();
  if (t < nbuk) hist_g[t * NBLK + blk] = cnt[t];
}

// ---------- per-bucket scan of NBLK partial counts (one block per bucket) ----------
__global__ __launch_bounds__(512) void scan_blk(const int* __restrict__ in,
                                                int* __restrict__ out,
                                                int* __restrict__ bsums, int nc) {
  int t = threadIdx.x;
  int i = blockIdx.x * NBLK + t;
  int v = (i < nc) ? in[i] : 0;
  int lane = t & 63, w = t >> 6;
  int s = v;
  #pragma unroll
  for (int off = 1; off < 64; off <<= 1) {
    int u = __shfl_up(s, off);
    if (lane >= off) s += u;
  }
  __shared__ int wsum[8];
  if (lane == 63) wsum[w] = s;
  __syncthreads();
  int add = 0;
  for (int k = 0; k < w; ++k) add += wsum[k];
  int incl = s + add;
  if (i < nc) out[i] = incl - v;
  if (t == NBLK - 1) bsums[blockIdx.x] = incl;
}

__global__ __launch_bounds__(1024) void scan_top(int* __restrict__ bsums, int nb) {
  int t = threadIdx.x;
  int v = (t < nb) ? bsums[t] : 0;
  int lane = t & 63, w = t >> 6;
  int s = v;
  #pragma unroll
  for (int off = 1; off < 64; off <<= 1) {
    int u = __shfl_up(s, off);
    if (lane >= off) s += u;
  }
  __shared__ int ws[16];
  if (lane == 63) ws[w] = s;
  __syncthreads();
  int add = 0;
  for (int k = 0; k < w; ++k) add += ws[k];
  if (t < nb) bsums[t] = s + add - v;
}

// ---------- scatter via LDS staging: dense per-run global writes ----------
__global__ __launch_bounds__(512) void escatter_kernel(
    const void* __restrict__ eidx, int E, int EP, int chunk,
    const int* __restrict__ flags, const int* __restrict__ hist_g,
    const int* __restrict__ pbase, const int* __restrict__ bsums,
    u32* __restrict__ pairs, int nbuk) {
  __shared__ int cnt[MAXBUK];
  __shared__ int lbase[MAXBUK];
  __shared__ int lcur[MAXBUK];
  __shared__ u32 buf[CHUNK_MAX];
  __shared__ int wsum[8];
  int t = threadIdx.x, blk = blockIdx.x;
  int v = 0;
  if (t < nbuk) { v = hist_g[t * NBLK + blk]; cnt[t] = v; }
  int lane = t & 63, w = t >> 6;
  int s = v;
  #pragma unroll
  for (int off = 1; off < 64; off <<= 1) {
    int u = __shfl_up(s, off);
    if (lane >= off) s += u;
  }
  if (lane == 63) wsum[w] = s;
  __syncthreads();
  int add = 0;
  for (int k = 0; k < w; ++k) add += wsum[k];
  if (t < nbuk) { lbase[t] = s + add - v; lcur[t] = s + add - v; }
  __syncthreads();
  int lo = blk * chunk, hi = min(lo + chunk, EP);
  int is64 = flags[0];
  for (int i = lo + t; i < hi; i += 512) {
    int sv, d;
    if (i < E) { sv = load_idx(eidx, i, is64); d = load_idx(eidx, E + i, is64); }
    else { sv = d = i - E; }
    int pos = atomicAdd(&lcur[d >> 8], 1);
    buf[pos] = ((u32)(d & 255) << 24) | (u32)sv;
  }
  __syncthreads();
  for (int b = w; b < nbuk; b += 8) {
    int n_b = cnt[b];
    int lb = lbase[b];
    int gb = pbase[b * NBLK + blk] + bsums[b];
    for (int k = lane; k < n_b; k += 64) {
      pairs[gb + k] = buf[lb + k];
    }
  }
}

// ---------- per-bucket local sort: LDS hist+scan, write offs/ends/ssrc ----------
__global__ __launch_bounds__(512) void bfinal_kernel(
    const u32* __restrict__ pairs, const int* __restrict__ pbase,
    const int* __restrict__ bsums,
    int* __restrict__ offs, int* __restrict__ ends, int* __restrict__ ssrc,
    int N, int EP, int nbuk) {
  int b = blockIdx.x, t = threadIdx.x;
  int nb0 = b << 8;
  __shared__ int cnt[256];
  __shared__ int cur[256];
  __shared__ int wsum[8];
  if (t < 256) cnt[t] = 0;
  __syncthreads();
  int seg_start = pbase[b * NBLK] + bsums[b];
  int seg_end = (b + 1 < nbuk) ? (pbase[(b + 1) * NBLK] + bsums[b + 1]) : EP;
  for (int i = seg_start + t; i < seg_end; i += 512) {
    atomicAdd(&cnt[pairs[i] >> 24], 1);
  }
  __syncthreads();
  int v = (t < 256) ? cnt[t] : 0;
  int lane = t & 63, w = t >> 6;
  int s = v;
  #pragma unroll
  for (int off = 1; off < 64; off <<= 1) {
    int u = __shfl_up(s, off);
    if (lane >= off) s += u;
  }
  if (lane == 63) wsum[w] = s;
  __syncthreads();
  int add = 0;
  for (int k = 0; k < w; ++k) add += wsum[k];
  int excl = s + add - v;
  if (t < 256) {
    cur[t] = excl;
    int node = nb0 + t;
    if (node < N) { offs[node] = seg_start + excl; ends[node] = seg_start + excl + v; }
  }
  __syncthreads();
  for (int i = seg_start + t; i < seg_end; i += 512) {
    u32 p = pairs[i];
    int pos = atomicAdd(&cur[p >> 24], 1);
    ssrc[seg_start + pos] = (int)(p & 0xFFFFFFu);
  }
}

// ---------- degree binning: hist -> scan -> two-phase scatter => perm ----------
__global__ __launch_bounds__(256) void dhist_kernel(
    const int* __restrict__ offs, const int* __restrict__ ends,
    int* __restrict__ gbin, int N) {
  __shared__ int lb[64];
  int t = threadIdx.x;
  if (t < 64) lb[t] = 0;
  __syncthreads();
  int i = blockIdx.x * 256 + t;
  if (i < N) {
    int b = min((ends[i] - offs[i]) >> 2, 63);
    atomicAdd(&lb[b], 1);
  }
  __syncthreads();
  if (t < 64 && lb[t]) atomicAdd(&gbin[t], lb[t]);
}

__global__ __launch_bounds__(64) void dscan_kernel(const int* __restrict__ gbin,
                                                   int* __restrict__ gcur) {
  int t = threadIdx.x;
  int v = gbin[t];
  int s = v;
  #pragma unroll
  for (int off = 1; off < 64; off <<= 1) {
    int u = __shfl_up(s, off);
    if (t >= off) s += u;
  }
  gcur[t] = s - v;   // exclusive
}

__global__ __launch_bounds__(256) void dscatter_kernel(
    const int* __restrict__ offs, const int* __restrict__ ends,
    int* __restrict__ gcur, int* __restrict__ perm, int N) {
  __shared__ int lb[64];
  __shared__ int lbase[64];
  int t = threadIdx.x;
  if (t < 64) lb[t] = 0;
  __syncthreads();
  int i = blockIdx.x * 256 + t;
  int b = 0, pos = 0;
  if (i < N) {
    b = min((ends[i] - offs[i]) >> 2, 63);
    pos = atomicAdd(&lb[b], 1);
  }
  __syncthreads();
  if (t < 64 && lb[t]) lbase[t] = atomicAdd(&gcur[t], lb[t]);
  __syncthreads();
  if (i < N) perm[lbase[b] + pos] = i;
}

// ---------- layer-1 aggregation + ELU + layer-2 projection ----------
// 16 lanes/node, 4 degree-matched nodes/wave; ssrc prefetched 1 step ahead.
__global__ __launch_bounds__(256) void node1_kernel(
    const int* __restrict__ perm,
    const int* __restrict__ ssrc, const int* __restrict__ offs, const int* __restrict__ ends,
    const u16* __restrict__ h, const float* __restrict__ a_src, const float* __restrict__ a_dst,
    const float* __restrict__ b1, const float* __restrict__ W2,
    const float* __restrict__ att_s2, const float* __restrict__ att_d2,
    float4* __restrict__ rec, int nn) {
  int t = threadIdx.x;
  int wid = t >> 6, lane = t & 63;
  int grp = lane >> 4, lg = lane & 15;      // 4 node-groups of 16 lanes
  int nidx = blockIdx.x * 16 + wid * 4 + grp;
  bool nvalid = (nidx < nn);
  int n = perm[nvalid ? nidx : 0];
  int hh = lg >> 1;                          // head for this lane's 8 dims
  float adst = a_dst[n * 8 + hh];
  int beg = offs[n], end = ends[n];
  int deg = nvalid ? (end - beg) : 0;
  int maxd = deg;
  maxd = max(maxd, __shfl_xor(maxd, 16));
  maxd = max(maxd, __shfl_xor(maxd, 32));    // wave-wide max degree (≈deg after binning)
  float acc[8];
  #pragma unroll
  for (int k = 0; k < 8; ++k) acc[k] = 0.f;
  float dsum = 0.f;
  const u32* h32 = (const u32*)h;

  int s4[4], ns4[4];
  #pragma unroll
  for (int u = 0; u < 4; ++u) {
    int id = beg + u;
    s4[u] = ssrc[id < end ? id : (end - 1)];
  }
  for (int it = 0; it < maxd; it += 4) {
    // prefetch next 4 indices (clamped -> always safe)
    #pragma unroll
    for (int u = 0; u < 4; ++u) {
      int id = beg + it + 4 + u;
      ns4[u] = ssrc[id < end ? id : (end - 1)];
    }
    float ea4[4]; uint4 v4[4];
    #pragma unroll
    for (int u = 0; u < 4; ++u) {
      v4[u]  = *(const uint4*)(h32 + s4[u] * 64 + lg * 4);
      ea4[u] = a_src[s4[u] * 8 + hh];
    }
    #pragma unroll
    for (int u = 0; u < 4; ++u) {
      float e = ea4[u] + adst;
      e = fmaxf(e, 0.2f * e);                 // leaky_relu
      float ee = (it + u < deg) ? __expf(e) : 0.f;
      dsum += ee;
      acc[0] = fmaf(ee, __uint_as_float(v4[u].x << 16),          acc[0]);
      acc[1] = fmaf(ee, __uint_as_float(v4[u].x & 0xFFFF0000u),  acc[1]);
      acc[2] = fmaf(ee, __uint_as_float(v4[u].y << 16),          acc[2]);
      acc[3] = fmaf(ee, __uint_as_float(v4[u].y & 0xFFFF0000u),  acc[3]);
      acc[4] = fmaf(ee, __uint_as_float(v4[u].z << 16),          acc[4]);
      acc[5] = fmaf(ee, __uint_as_float(v4[u].z & 0xFFFF0000u),  acc[5]);
      acc[6] = fmaf(ee, __uint_as_float(v4[u].w << 16),          acc[6]);
      acc[7] = fmaf(ee, __uint_as_float(v4[u].w & 0xFFFF0000u),  acc[7]);
    }
    #pragma unroll
    for (int u = 0; u < 4; ++u) s4[u] = ns4[u];
  }
  float inv = 1.f / dsum;                     // lane-local denominator
  float p0 = 0.f, p1 = 0.f;
  #pragma unroll
  for (int k = 0; k < 8; ++k) {
    int j = lg * 8 + k;
    float o = acc[k] * inv + b1[j];
    o = (o > 0.f) ? o : expm1f(o);            // ELU
    p0 = fmaf(o, W2[j * 2],     p0);
    p1 = fmaf(o, W2[j * 2 + 1], p1);
  }
  #pragma unroll
  for (int m = 1; m < 16; m <<= 1) { p0 += __shfl_xor(p0, m); p1 += __shfl_xor(p1, m); }
  if (nvalid && lg == 0) {
    rec[n] = make_float4(p0, p1,
                         p0 * att_s2[0] + p1 * att_s2[1],
                         p0 * att_d2[0] + p1 * att_d2[1]);
  }
}

// ---------- layer-2 aggregation + graph mean-pool (8-lane group per node) ----------
__global__ __launch_bounds__(256) void node2_kernel(
    const int* __restrict__ ssrc, const int* __restrict__ offs, const int* __restrict__ ends,
    const float4* __restrict__ rec, const float* __restrict__ b2,
    const void* __restrict__ batch, const int* __restrict__ flags,
    float* __restrict__ pool, int nn) {
  __shared__ float psum[128];
  __shared__ float pcnt[64];
  int t = threadIdx.x;
  if (t < 128) psum[t] = 0.f;
  if (t < 64) pcnt[t] = 0.f;
  __syncthreads();
  int grp = t >> 3, lane8 = t & 7;    // 32 groups of 8 lanes
  int b64 = flags[1];
  int n = blockIdx.x * 32 + grp;
  if (n < nn) {
    float adst = rec[n].w;
    int beg = offs[n], end = ends[n];
    float acc0 = 0.f, acc1 = 0.f, dsum = 0.f;
    for (int idx = beg + lane8; idx < end; idx += 8) {
      int s = ssrc[idx];
      float4 r = rec[s];                // one 16B gather: {p0,p1,as2,ad2}
      float e = r.z + adst;
      e = (e < 0.f) ? 0.2f * e : e;
      float ee = __expf(e);
      acc0 = fmaf(ee, r.x, acc0);
      acc1 = fmaf(ee, r.y, acc1);
      dsum += ee;
    }
    #pragma unroll
    for (int m = 1; m < 8; m <<= 1) {
      acc0 += __shfl_xor(acc0, m);
      acc1 += __shfl_xor(acc1, m);
      dsum += __shfl_xor(dsum, m);
    }
    if (lane8 == 0) {
      float o0 = acc0 / dsum + b2[0];
      float o1 = acc1 / dsum + b2[1];
      int g = load_idx(batch, n, b64);
      atomicAdd(&psum[g * 2], o0);
      atomicAdd(&psum[g * 2 + 1], o1);
      atomicAdd(&pcnt[g], 1.f);
    }
  }
  __syncthreads();
  if (t < 64 && pcnt[t] > 0.f) {
    atomicAdd(&pool[t * 2], psum[t * 2]);
    atomicAdd(&pool[t * 2 + 1], psum[t * 2 + 1]);
    atomicAdd(&pool[128 + t], pcnt[t]);
  }
}

// ---------- mean + log_softmax ----------
__global__ void finalize_kernel(const float* __restrict__ pool, float* __restrict__ out) {
  int g = threadIdx.x;
  if (g < 64) {
    float c = fmaxf(pool[128 + g], 1.f);
    float p0 = pool[g * 2] / c, p1 = pool[g * 2 + 1] / c;
    float m = fmaxf(p0, p1);
    float lse = m + logf(expf(p0 - m) + expf(p1 - m));
    out[g * 2] = p0 - lse;
    out[g * 2 + 1] = p1 - lse;
  }
}

extern "C" void kernel_launch(void* const* d_in, const int* in_sizes, int n_in,
                              void* d_out, int out_size, void* d_ws, size_t ws_size,
                              hipStream_t stream) {
  const float* x        = (const float*)d_in[0];
  const void* eidx      = d_in[1];
  const void* batch     = d_in[2];
  const float* W1       = (const float*)d_in[3];
  const float* att_src1 = (const float*)d_in[4];
  const float* att_dst1 = (const float*)d_in[5];
  const float* b1       = (const float*)d_in[6];
  const float* W2       = (const float*)d_in[7];
  const float* att_src2 = (const float*)d_in[8];
  const float* att_dst2 = (const float*)d_in[9];
  const float* b2       = (const float*)d_in[10];
  float* out = (float*)d_out;

  int N = in_sizes[0] / 128;
  int E = in_sizes[1] / 2;
  int EP = E + N;
  int NBUK = (N + 255) >> 8;         // <= MAXBUK for N <= 131072
  int NC = NBUK * NBLK;
  int chunk = (((EP + NBLK - 1) / NBLK) + 1) & ~1;   // <= CHUNK_MAX

  char* ws = (char*)d_ws;
  size_t o = 0;
  auto alloc = [&](size_t bytes) -> void* {
    void* p = ws + o;
    o += (bytes + 255) & ~(size_t)255;
    return p;
  };
  u16*   h      = (u16*)alloc((size_t)N * 128 * 2);    // 25.6 MB bf16
  u16*   Wtb    = (u16*)alloc(128 * 128 * 2);          // bf16 W1^T
  float* a_src1 = (float*)alloc((size_t)N * 8 * 4);
  float* a_dst1 = (float*)alloc((size_t)N * 8 * 4);
  int*   offs   = (int*)alloc((size_t)N * 4);
  int*   ends   = (int*)alloc((size_t)N * 4);
  int*   hist_g = (int*)alloc((size_t)NC * 4);         // 800 KB
  int*   pbase  = (int*)alloc((size_t)NC * 4);
  int*   bsums  = (int*)alloc((size_t)(NBUK + 1) * 4);
  u32*   pairs  = (u32*)alloc((size_t)EP * 4);         // 6.8 MB packed
  int*   ssrc   = (int*)alloc((size_t)EP * 4);
  int*   perm   = (int*)alloc((size_t)N * 4);
  int*   gbin   = (int*)alloc(64 * 4);
  int*   gcur   = (int*)alloc(64 * 4);
  float4* rec   = (float4*)alloc((size_t)N * 16);      // {p0,p1,as2,ad2}
  float* pool   = (float*)alloc(192 * 4);
  int*   flags  = (int*)alloc(2 * 4);

  prep_kernel<<<65, 256, 0, stream>>>(eidx, 2 * E, batch, N, W1, Wtb, pool, gbin, flags);
  gemm1_kernel<<<(N + 63) / 64, 256, 0, stream>>>(x, Wtb, att_src1, att_dst1,
                                                  h, a_src1, a_dst1, N);
  ehist_kernel<<<NBLK, 512, 0, stream>>>(eidx, E, EP, chunk, flags, hist_g, NBUK);
  scan_blk<<<NBUK, 512, 0, stream>>>(hist_g, pbase, bsums, NC);
  scan_top<<<1, 1024, 0, stream>>>(bsums, NBUK);
  escatter_kernel<<<NBLK, 512, 0, stream>>>(eidx, E, EP, chunk, flags, hist_g,
                                            pbase, bsums, pairs, NBUK);
  bfinal_kernel<<<NBUK, 512, 0, stream>>>(pairs, pbase, bsums, offs, ends, ssrc,
                                          N, EP, NBUK);
  dhist_kernel<<<(N + 255) / 256, 256, 0, stream>>>(offs, ends, gbin, N);
  dscan_kernel<<<1, 64, 0, stream>>>(gbin, gcur);
  dscatter_kernel<<<(N + 255) / 256, 256, 0, stream>>>(offs, ends, gcur, perm, N);
  node1_kernel<<<(N + 15) / 16, 256, 0, stream>>>(perm, ssrc, offs, ends, h,
                                                  a_src1, a_dst1, b1, W2,
                                                  att_src2, att_dst2, rec, N);
  node2_kernel<<<(N + 31) / 32, 256, 0, stream>>>(ssrc, offs, ends, rec,
                                                  b2, batch, flags, pool, N);
  finalize_kernel<<<1, 64, 0, stream>>>(pool, out);
}

// Round 11
// 203.638 us; speedup vs baseline: 1.0670x; 1.0670x over previous
//
#include <hip/hip_runtime.h>
#include <math.h>

typedef long long ll;
typedef unsigned int u32;
typedef unsigned short u16;
typedef __attribute__((ext_vector_type(8))) short short8;
typedef __attribute__((ext_vector_type(4))) float f32x4;

#define NBLK 256          // partition blocks
#define MAXBUK 512        // supports N <= 131072
#define CHUNK_MAX 8192    // LDS edge buffer in escatter
#define SBUF 5120         // per-half-bucket LDS edge list (mean 2176, +64 sigma)

__device__ __forceinline__ int load_idx(const void* p, int i, int is64) {
  return is64 ? (int)((const ll*)p)[i] : ((const int*)p)[i];
}

__device__ __forceinline__ u16 f2bf(float f) {
  u32 u = __float_as_uint(f);
  u += 0x7FFFu + ((u >> 16) & 1u);
  return (u16)(u >> 16);
}

// ---------- prep: W1->bf16^T + detect(parallel) + zero pool ----------
__global__ __launch_bounds__(256) void prep_kernel(
    const void* __restrict__ eidx, int ne2, const void* __restrict__ batch, int nb,
    const float* __restrict__ W1, u16* __restrict__ Wtb,
    float* __restrict__ pool, int* __restrict__ flags) {
  int blk = blockIdx.x, t = threadIdx.x;
  if (blk < 64) {
    int g = blk * 256 + t;          // 16384 elements of W1[k][j]
    int k = g >> 7, j = g & 127;
    Wtb[j * 128 + k] = f2bf(W1[g]);
  } else {
    if (t < 192) pool[t] = 0.f;
    ll v = 0;
    if (t < 16) {
      int i = (int)((ll)(t + 1) * (ne2 / 2 - 1) / 16);
      v = ((const ll*)eidx)[i];
    } else if (t < 32) {
      int i = (int)((ll)(t - 15) * (nb / 2 - 1) / 16);
      v = ((const ll*)batch)[i];
    }
    bool bad = (v < 0 || v >= (1LL << 31));
    unsigned long long mask = __ballot(bad);
    if (t == 0) {
      flags[0] = (mask & 0xFFFFull) ? 0 : 1;          // edge_index is64
      flags[1] = (mask & 0xFFFF0000ull) ? 0 : 1;      // batch is64
    }
  }
}

// ---------- K1: h = x @ W1 via MFMA bf16 (f32 acc; fused a_src1/a_dst1) ----------
__global__ __launch_bounds__(256) void gemm1_kernel(
    const float* __restrict__ x, const u16* __restrict__ Wtb,
    const float* __restrict__ att_src, const float* __restrict__ att_dst,
    u16* __restrict__ h, float* __restrict__ a_src, float* __restrict__ a_dst,
    int nn) {
  __shared__ __align__(16) char smem[64 * 136 * 2 + 128 * 136 * 2];  // 52224 B
  u16* xs = (u16*)smem;                       // [64][136]
  u16* Wt = (u16*)(smem + 64 * 136 * 2);      // [128][136]  Wt[j][k]
  float* hs = (float*)smem;                   // [64][132]   (overlay)
  int t = threadIdx.x;
  int n0 = blockIdx.x * 64;

  const uint4* W4 = (const uint4*)Wtb;        // 2048 uint4
  #pragma unroll
  for (int p = 0; p < 8; ++p) {
    int i = t + p * 256;
    int j = i >> 4, kc = (i & 15) * 8;
    *(uint4*)&Wt[j * 136 + kc] = W4[i];
  }
  #pragma unroll
  for (int p = 0; p < 4; ++p) {
    int row = p * 16 + (t >> 4);
    int c = t & 15;
    int gn = n0 + row;
    uint4 pk = make_uint4(0u, 0u, 0u, 0u);
    if (gn < nn) {
      const float4* xp = (const float4*)(x + (size_t)gn * 128 + c * 8);
      float4 f0 = xp[0], f1 = xp[1];
      pk.x = (u32)f2bf(f0.x) | ((u32)f2bf(f0.y) << 16);
      pk.y = (u32)f2bf(f0.z) | ((u32)f2bf(f0.w) << 16);
      pk.z = (u32)f2bf(f1.x) | ((u32)f2bf(f1.y) << 16);
      pk.w = (u32)f2bf(f1.z) | ((u32)f2bf(f1.w) << 16);
    }
    *(uint4*)&xs[row * 136 + c * 8] = pk;
  }
  __syncthreads();

  int lane = t & 63, wid = t >> 6;
  int lrow = lane & 15, lq = lane >> 4;
  short8 a[4];
  #pragma unroll
  for (int ks = 0; ks < 4; ++ks) {
    int row = wid * 16 + lrow;
    a[ks] = *(const short8*)&xs[row * 136 + ks * 32 + lq * 8];
  }
  f32x4 c[8];
  #pragma unroll
  for (int jt = 0; jt < 8; ++jt) c[jt] = (f32x4)(0.f);
  #pragma unroll
  for (int jt = 0; jt < 8; ++jt) {
    int j = jt * 16 + lrow;
    #pragma unroll
    for (int ks = 0; ks < 4; ++ks) {
      short8 b = *(const short8*)&Wt[j * 136 + ks * 32 + lq * 8];
      c[jt] = __builtin_amdgcn_mfma_f32_16x16x32_bf16(a[ks], b, c[jt], 0, 0, 0);
    }
  }
  __syncthreads();

  #pragma unroll
  for (int jt = 0; jt < 8; ++jt) {
    #pragma unroll
    for (int r = 0; r < 4; ++r) {
      hs[(wid * 16 + lq * 4 + r) * 132 + jt * 16 + lrow] = c[jt][r];
    }
  }
  __syncthreads();

  int q = t & 31, p = t >> 5;
  const float4 as4 = ((const float4*)att_src)[q];
  const float4 ad4 = ((const float4*)att_dst)[q];
  int head = q >> 2;
  #pragma unroll
  for (int rr = 0; rr < 8; ++rr) {
    int row = rr * 8 + p;
    int n = n0 + row;
    float4 v = *(const float4*)&hs[row * 132 + q * 4];
    float s = v.x * as4.x + v.y * as4.y + v.z * as4.z + v.w * as4.w;
    float d = v.x * ad4.x + v.y * ad4.y + v.z * ad4.z + v.w * ad4.w;
    s += __shfl_xor(s, 1); s += __shfl_xor(s, 2);
    d += __shfl_xor(d, 1); d += __shfl_xor(d, 2);
    if (n < nn) {
      uint2 pk;
      pk.x = (u32)f2bf(v.x) | ((u32)f2bf(v.y) << 16);
      pk.y = (u32)f2bf(v.z) | ((u32)f2bf(v.w) << 16);
      ((uint2*)(h + (size_t)n * 128))[q] = pk;
      if ((q & 3) == 0) { a_src[n * 8 + head] = s; a_dst[n * 8 + head] = d; }
    }
  }
}

// ---------- per-block LDS histogram of dst buckets ----------
__global__ __launch_bounds__(512) void ehist_kernel(
    const void* __restrict__ eidx, int E, int EP, int chunk,
    const int* __restrict__ flags, int* __restrict__ hist_g, int nbuk) {
  __shared__ int cnt[MAXBUK];
  int t = threadIdx.x, blk = blockIdx.x;
  if (t < MAXBUK) cnt[t] = 0;
  __syncthreads();
  int lo = blk * chunk, hi = min(lo + chunk, EP);
  int is64 = flags[0];
  for (int i = lo + t; i < hi; i += 512) {
    int d = (i < E) ? load_idx(eidx, E + i, is64) : (i - E);
    atomicAdd(&cnt[d >> 8], 1);
  }
  __syncthreads();
  if (t < nbuk) hist_g[t * NBLK + blk] = cnt[t];
}

// ---------- per-bucket scan of NBLK partial counts ----------
__global__ __launch_bounds__(256) void scan_blk(const int* __restrict__ in,
                                                int* __restrict__ out,
                                                int* __restrict__ bsums, int n) {
  int t = threadIdx.x;
  int i = blockIdx.x * 256 + t;
  int v = (i < n) ? in[i] : 0;
  int lane = t & 63, w = t >> 6;
  int s = v;
  #pragma unroll
  for (int off = 1; off < 64; off <<= 1) {
    int u = __shfl_up(s, off);
    if (lane >= off) s += u;
  }
  __shared__ int wsum[4];
  if (lane == 63) wsum[w] = s;
  __syncthreads();
  int add = 0;
  for (int k = 0; k < w; ++k) add += wsum[k];
  int incl = s + add;
  if (i < n) out[i] = incl - v;
  if (t == 255) bsums[blockIdx.x] = incl;
}

__global__ __launch_bounds__(1024) void scan_top(int* __restrict__ bsums, int nb) {
  int t = threadIdx.x;
  int v = (t < nb) ? bsums[t] : 0;
  int lane = t & 63, w = t >> 6;
  int s = v;
  #pragma unroll
  for (int off = 1; off < 64; off <<= 1) {
    int u = __shfl_up(s, off);
    if (lane >= off) s += u;
  }
  __shared__ int ws[16];
  if (lane == 63) ws[w] = s;
  __syncthreads();
  int add = 0;
  for (int k = 0; k < w; ++k) add += ws[k];
  if (t < nb) bsums[t] = s + add - v;
}

// ---------- scatter via LDS staging: dense per-run global writes ----------
__global__ __launch_bounds__(512) void escatter_kernel(
    const void* __restrict__ eidx, int E, int EP, int chunk,
    const int* __restrict__ flags, const int* __restrict__ hist_g,
    const int* __restrict__ pbase, const int* __restrict__ bsums,
    u32* __restrict__ pairs, int nbuk) {
  __shared__ int cnt[MAXBUK];
  __shared__ int lbase[MAXBUK];
  __shared__ int lcur[MAXBUK];
  __shared__ u32 buf[CHUNK_MAX];
  __shared__ int wsum[8];
  int t = threadIdx.x, blk = blockIdx.x;
  int v = 0;
  if (t < nbuk) { v = hist_g[t * NBLK + blk]; cnt[t] = v; }
  int lane = t & 63, w = t >> 6;
  int s = v;
  #pragma unroll
  for (int off = 1; off < 64; off <<= 1) {
    int u = __shfl_up(s, off);
    if (lane >= off) s += u;
  }
  if (lane == 63) wsum[w] = s;
  __syncthreads();
  int add = 0;
  for (int k = 0; k < w; ++k) add += wsum[k];
  if (t < nbuk) { lbase[t] = s + add - v; lcur[t] = s + add - v; }
  __syncthreads();
  int lo = blk * chunk, hi = min(lo + chunk, EP);
  int is64 = flags[0];
  for (int i = lo + t; i < hi; i += 512) {
    int sv, d;
    if (i < E) { sv = load_idx(eidx, i, is64); d = load_idx(eidx, E + i, is64); }
    else { sv = d = i - E; }
    int pos = atomicAdd(&lcur[d >> 8], 1);
    buf[pos] = ((u32)(d & 255) << 24) | (u32)sv;
  }
  __syncthreads();
  for (int b = w; b < nbuk; b += 8) {
    int n_b = cnt[b];
    int lb = lbase[b];
    int gb = pbase[b * NBLK + blk] + bsums[b];
    for (int k = lane; k < n_b; k += 64) {
      pairs[gb + k] = buf[lb + k];
    }
  }
}

// ---------- fused node1: LDS bucket sort + aggregation + ELU + L2 projection ----------
// one block per HALF-bucket (128 nodes), 512 thr = 8 waves; 16 lanes/node.
__global__ __launch_bounds__(512) void node1_kernel(
    const u32* __restrict__ pairs, const int* __restrict__ bsums,
    const u16* __restrict__ h, const float* __restrict__ a_src, const float* __restrict__ a_dst,
    const float* __restrict__ b1, const float* __restrict__ W2,
    const float* __restrict__ att_s2, const float* __restrict__ att_d2,
    float4* __restrict__ rec, int N, int EP, int nbuk) {
  __shared__ int lcnt[128], lofs[128], lcur[128];
  __shared__ int wsum[2];
  __shared__ u32 sbuf[SBUF];
  int blk = blockIdx.x;
  int b = blk >> 1, hbase = (blk & 1) << 7;
  int t = threadIdx.x;
  if (t < 128) lcnt[t] = 0;
  __syncthreads();
  int seg_start = bsums[b];
  int seg_end = (b + 1 < nbuk) ? bsums[b + 1] : EP;
  for (int i = seg_start + t; i < seg_end; i += 512) {
    int ld = (int)(pairs[i] >> 24);
    if ((ld & 128) == hbase) atomicAdd(&lcnt[ld & 127], 1);
  }
  __syncthreads();
  int v = 0, sincl = 0;
  if (t < 128) {
    v = lcnt[t];
    sincl = v;
    #pragma unroll
    for (int off = 1; off < 64; off <<= 1) {
      int u = __shfl_up(sincl, off);
      if ((t & 63) >= off) sincl += u;
    }
    if ((t & 63) == 63) wsum[t >> 6] = sincl;
  }
  __syncthreads();
  if (t < 128) {
    int add = (t >= 64) ? wsum[0] : 0;
    int excl = sincl + add - v;
    lofs[t] = excl; lcur[t] = excl;
  }
  __syncthreads();
  for (int i = seg_start + t; i < seg_end; i += 512) {
    u32 p = pairs[i];
    int ld = (int)(p >> 24);
    if ((ld & 128) == hbase) {
      int pos = atomicAdd(&lcur[ld & 127], 1);
      if (pos < SBUF) sbuf[pos] = p & 0xFFFFFFu;
    }
  }
  __syncthreads();

  int wid = t >> 6, lane = t & 63;
  int grp = lane >> 4, lg = lane & 15;
  int hh = lg >> 1;
  const u32* h32 = (const u32*)h;
  #pragma unroll 1
  for (int pass = 0; pass < 4; ++pass) {
    int ln = pass * 32 + wid * 4 + grp;          // 0..127
    int n = (b << 8) + hbase + ln;
    bool nvalid = (n < N);
    int beg = 0, deg = 0;
    if (nvalid) {
      beg = lofs[ln]; deg = lcnt[ln];
      if (beg >= SBUF) deg = 0; else deg = min(deg, SBUF - beg);
    }
    int maxd = deg;
    maxd = max(maxd, __shfl_xor(maxd, 16));
    maxd = max(maxd, __shfl_xor(maxd, 32));
    float adst = nvalid ? a_dst[n * 8 + hh] : 0.f;
    float acc[8];
    #pragma unroll
    for (int k = 0; k < 8; ++k) acc[k] = 0.f;
    float dsum = 0.f;
    for (int it = 0; it < maxd; it += 4) {
      int s4[4]; float ea4[4]; uint4 v4[4];
      #pragma unroll
      for (int u = 0; u < 4; ++u) {
        int id = it + u;
        int cl = (id < deg) ? id : (deg > 0 ? deg - 1 : 0);
        s4[u] = (deg > 0) ? (int)sbuf[beg + cl] : 0;
      }
      #pragma unroll
      for (int u = 0; u < 4; ++u) {
        v4[u]  = *(const uint4*)(h32 + s4[u] * 64 + lg * 4);
        ea4[u] = a_src[s4[u] * 8 + hh];
      }
      #pragma unroll
      for (int u = 0; u < 4; ++u) {
        float e = ea4[u] + adst;
        e = fmaxf(e, 0.2f * e);                 // leaky_relu
        float ee = (it + u < deg) ? __expf(e) : 0.f;
        dsum += ee;
        acc[0] = fmaf(ee, __uint_as_float(v4[u].x << 16),          acc[0]);
        acc[1] = fmaf(ee, __uint_as_float(v4[u].x & 0xFFFF0000u),  acc[1]);
        acc[2] = fmaf(ee, __uint_as_float(v4[u].y << 16),          acc[2]);
        acc[3] = fmaf(ee, __uint_as_float(v4[u].y & 0xFFFF0000u),  acc[3]);
        acc[4] = fmaf(ee, __uint_as_float(v4[u].z << 16),          acc[4]);
        acc[5] = fmaf(ee, __uint_as_float(v4[u].z & 0xFFFF0000u),  acc[5]);
        acc[6] = fmaf(ee, __uint_as_float(v4[u].w << 16),          acc[6]);
        acc[7] = fmaf(ee, __uint_as_float(v4[u].w & 0xFFFF0000u),  acc[7]);
      }
    }
    if (nvalid && deg > 0) {
      float inv = 1.f / dsum;
      float p0 = 0.f, p1 = 0.f;
      #pragma unroll
      for (int k = 0; k < 8; ++k) {
        int j = lg * 8 + k;
        float o = acc[k] * inv + b1[j];
        o = (o > 0.f) ? o : expm1f(o);          // ELU
        p0 = fmaf(o, W2[j * 2],     p0);
        p1 = fmaf(o, W2[j * 2 + 1], p1);
      }
      #pragma unroll
      for (int m = 1; m < 16; m <<= 1) { p0 += __shfl_xor(p0, m); p1 += __shfl_xor(p1, m); }
      if (lg == 0) {
        rec[n] = make_float4(p0, p1,
                             p0 * att_s2[0] + p1 * att_s2[1],
                             p0 * att_d2[0] + p1 * att_d2[1]);
      }
    }
  }
}

// ---------- fused node2: LDS bucket sort + aggregation + mean-pool ----------
// one block per HALF-bucket (128 nodes), 512 thr; 8 lanes/node, 2 passes.
__global__ __launch_bounds__(512) void node2_kernel(
    const u32* __restrict__ pairs, const int* __restrict__ bsums,
    const float4* __restrict__ rec, const float* __restrict__ b2,
    const void* __restrict__ batch, const int* __restrict__ flags,
    float* __restrict__ pool, int N, int EP, int nbuk) {
  __shared__ int lcnt[128], lofs[128], lcur[128];
  __shared__ int wsum[2];
  __shared__ u32 sbuf[SBUF];
  __shared__ float psum[128];
  __shared__ float pcnt[64];
  int blk = blockIdx.x;
  int b = blk >> 1, hbase = (blk & 1) << 7;
  int t = threadIdx.x;
  if (t < 128) { lcnt[t] = 0; psum[t] = 0.f; }
  if (t < 64) pcnt[t] = 0.f;
  __syncthreads();
  int seg_start = bsums[b];
  int seg_end = (b + 1 < nbuk) ? bsums[b + 1] : EP;
  for (int i = seg_start + t; i < seg_end; i += 512) {
    int ld = (int)(pairs[i] >> 24);
    if ((ld & 128) == hbase) atomicAdd(&lcnt[ld & 127], 1);
  }
  __syncthreads();
  int v = 0, sincl = 0;
  if (t < 128) {
    v = lcnt[t];
    sincl = v;
    #pragma unroll
    for (int off = 1; off < 64; off <<= 1) {
      int u = __shfl_up(sincl, off);
      if ((t & 63) >= off) sincl += u;
    }
    if ((t & 63) == 63) wsum[t >> 6] = sincl;
  }
  __syncthreads();
  if (t < 128) {
    int add = (t >= 64) ? wsum[0] : 0;
    int excl = sincl + add - v;
    lofs[t] = excl; lcur[t] = excl;
  }
  __syncthreads();
  for (int i = seg_start + t; i < seg_end; i += 512) {
    u32 p = pairs[i];
    int ld = (int)(p >> 24);
    if ((ld & 128) == hbase) {
      int pos = atomicAdd(&lcur[ld & 127], 1);
      if (pos < SBUF) sbuf[pos] = p & 0xFFFFFFu;
    }
  }
  __syncthreads();

  int grp = t >> 3, lane8 = t & 7;    // 64 groups of 8 lanes
  int b64 = flags[1];
  #pragma unroll 1
  for (int pass = 0; pass < 2; ++pass) {
    int ln = pass * 64 + grp;                    // 0..127
    int n = (b << 8) + hbase + ln;
    if (n < N) {
      int beg = lofs[ln], deg = lcnt[ln];
      if (beg >= SBUF) deg = 0; else deg = min(deg, SBUF - beg);
      float adst = rec[n].w;
      float acc0 = 0.f, acc1 = 0.f, dsum = 0.f;
      for (int idx = lane8; idx < deg; idx += 8) {
        int s = (int)sbuf[beg + idx];
        float4 r = rec[s];
        float e = r.z + adst;
        e = (e < 0.f) ? 0.2f * e : e;
        float ee = __expf(e);
        acc0 = fmaf(ee, r.x, acc0);
        acc1 = fmaf(ee, r.y, acc1);
        dsum += ee;
      }
      #pragma unroll
      for (int m = 1; m < 8; m <<= 1) {
        acc0 += __shfl_xor(acc0, m);
        acc1 += __shfl_xor(acc1, m);
        dsum += __shfl_xor(dsum, m);
      }
      if (lane8 == 0 && deg > 0) {
        float o0 = acc0 / dsum + b2[0];
        float o1 = acc1 / dsum + b2[1];
        int g = load_idx(batch, n, b64);
        atomicAdd(&psum[g * 2], o0);
        atomicAdd(&psum[g * 2 + 1], o1);
        atomicAdd(&pcnt[g], 1.f);
      }
    }
  }
  __syncthreads();
  if (t < 64 && pcnt[t] > 0.f) {
    atomicAdd(&pool[t * 2], psum[t * 2]);
    atomicAdd(&pool[t * 2 + 1], psum[t * 2 + 1]);
    atomicAdd(&pool[128 + t], pcnt[t]);
  }
}

// ---------- mean + log_softmax ----------
__global__ void finalize_kernel(const float* __restrict__ pool, float* __restrict__ out) {
  int g = threadIdx.x;
  if (g < 64) {
    float c = fmaxf(pool[128 + g], 1.f);
    float p0 = pool[g * 2] / c, p1 = pool[g * 2 + 1] / c;
    float m = fmaxf(p0, p1);
    float lse = m + logf(expf(p0 - m) + expf(p1 - m));
    out[g * 2] = p0 - lse;
    out[g * 2 + 1] = p1 - lse;
  }
}

extern "C" void kernel_launch(void* const* d_in, const int* in_sizes, int n_in,
                              void* d_out, int out_size, void* d_ws, size_t ws_size,
                              hipStream_t stream) {
  const float* x        = (const float*)d_in[0];
  const void* eidx      = d_in[1];
  const void* batch     = d_in[2];
  const float* W1       = (const float*)d_in[3];
  const float* att_src1 = (const float*)d_in[4];
  const float* att_dst1 = (const float*)d_in[5];
  const float* b1       = (const float*)d_in[6];
  const float* W2       = (const float*)d_in[7];
  const float* att_src2 = (const float*)d_in[8];
  const float* att_dst2 = (const float*)d_in[9];
  const float* b2       = (const float*)d_in[10];
  float* out = (float*)d_out;

  int N = in_sizes[0] / 128;
  int E = in_sizes[1] / 2;
  int EP = E + N;
  int NBUK = (N + 255) >> 8;         // <= MAXBUK for N <= 131072
  int NHB  = (N + 127) >> 7;         // half-buckets
  int NC = NBUK * NBLK;
  int chunk = (((EP + NBLK - 1) / NBLK) + 1) & ~1;   // <= CHUNK_MAX

  char* ws = (char*)d_ws;
  size_t o = 0;
  auto alloc = [&](size_t bytes) -> void* {
    void* p = ws + o;
    o += (bytes + 255) & ~(size_t)255;
    return p;
  };
  u16*   h      = (u16*)alloc((size_t)N * 128 * 2);    // 25.6 MB bf16
  u16*   Wtb    = (u16*)alloc(128 * 128 * 2);          // bf16 W1^T
  float* a_src1 = (float*)alloc((size_t)N * 8 * 4);
  float* a_dst1 = (float*)alloc((size_t)N * 8 * 4);
  int*   hist_g = (int*)alloc((size_t)NC * 4);         // 400 KB
  int*   pbase  = (int*)alloc((size_t)NC * 4);
  int*   bsums  = (int*)alloc((size_t)(NBUK + 1) * 4);
  u32*   pairs  = (u32*)alloc((size_t)EP * 4);         // 6.8 MB packed
  float4* rec   = (float4*)alloc((size_t)N * 16);      // {p0,p1,as2,ad2}
  float* pool   = (float*)alloc(192 * 4);
  int*   flags  = (int*)alloc(2 * 4);

  prep_kernel<<<65, 256, 0, stream>>>(eidx, 2 * E, batch, N, W1, Wtb, pool, flags);
  gemm1_kernel<<<(N + 63) / 64, 256, 0, stream>>>(x, Wtb, att_src1, att_dst1,
                                                  h, a_src1, a_dst1, N);
  ehist_kernel<<<NBLK, 512, 0, stream>>>(eidx, E, EP, chunk, flags, hist_g, NBUK);
  scan_blk<<<NBUK, 256, 0, stream>>>(hist_g, pbase, bsums, NC);
  scan_top<<<1, 1024, 0, stream>>>(bsums, NBUK);
  escatter_kernel<<<NBLK, 512, 0, stream>>>(eidx, E, EP, chunk, flags, hist_g,
                                            pbase, bsums, pairs, NBUK);
  node1_kernel<<<NHB, 512, 0, stream>>>(pairs, bsums, h, a_src1, a_dst1,
                                        b1, W2, att_src2, att_dst2,
                                        rec, N, EP, NBUK);
  node2_kernel<<<NHB, 512, 0, stream>>>(pairs, bsums, rec, b2, batch, flags,
                                        pool, N, EP, NBUK);
  finalize_kernel<<<1, 64, 0, stream>>>(pool, out);
}